// Round 3
// baseline (113.729 us; speedup 1.0000x reference)
//
#include <hip/hip_runtime.h>
#include <hip/hip_bf16.h>

#define B_    4096
#define D_    512
#define TB_   8192        // 2B rows
#define BM    128
#define BK    64
#define NK    (D_ / BK)   // 8 K-tiles
#define NTILE 64          // TB_/BM
#define NTRI  2080        // NTILE*(NTILE+1)/2
#define INV_T 14.285714285714286f   // 1/0.07

typedef __attribute__((ext_vector_type(8))) short bf16x8;
typedef __attribute__((ext_vector_type(4))) float f32x4;
typedef __attribute__((ext_vector_type(8))) unsigned short ushort8;

// async global->LDS, 16B per lane; LDS dest is wave-uniform base + lane*16
#define GLOAD_LDS16(gp, lp)                                                        \
  __builtin_amdgcn_global_load_lds((const __attribute__((address_space(1))) void*)(gp), \
                                   (__attribute__((address_space(3))) void*)(lp),  \
                                   16, 0, 0)

__device__ __forceinline__ unsigned short f2bf(float f) {
  unsigned int x = __float_as_uint(f);
  x += 0x7fffu + ((x >> 16) & 1u);   // round-to-nearest-even
  return (unsigned short)(x >> 16);
}

// ---------------------------------------------------------------------------
// Kernel 1: concat+cast fp32 -> bf16 (E[8192][512]), zero L[8192].
// ---------------------------------------------------------------------------
__global__ void ntx_prep(const float* __restrict__ a, const float* __restrict__ b,
                         unsigned short* __restrict__ E, float* __restrict__ L) {
  int t = blockIdx.x * blockDim.x + threadIdx.x;      // 0..524287
  int i = t * 8;
  const float* src = (i < B_ * D_) ? (a + i) : (b + (i - B_ * D_));
  float4 v0 = ((const float4*)src)[0];
  float4 v1 = ((const float4*)src)[1];
  ushort8 o;
  o[0] = f2bf(v0.x); o[1] = f2bf(v0.y); o[2] = f2bf(v0.z); o[3] = f2bf(v0.w);
  o[4] = f2bf(v1.x); o[5] = f2bf(v1.y); o[6] = f2bf(v1.z); o[7] = f2bf(v1.w);
  *(ushort8*)(E + i) = o;
  if (t < TB_) L[t] = 0.0f;
}

// ---------------------------------------------------------------------------
// Kernel 2: fused sim + exp row/col sums, triangular tiles, PIPELINED:
// double-buffered LDS (2x32KB -> 2 blocks/CU), raw s_barrier + counted
// vmcnt(4) so prefetch stays in flight across barriers (no full drain).
// Per K-tile: phase0 {issue next-A, vmcnt(4), barrier, sched_barrier,
// 16 MFMA ks=0}, phase1 {issue next-B, 16 MFMA ks=1, barrier}.
// pos tiles (tj==ti+32) also write pos[r] = s[r][r+B]/..*INV_T.
// ---------------------------------------------------------------------------
__global__ __launch_bounds__(256, 2)
void ntx_sim(const unsigned short* __restrict__ E, float* __restrict__ L,
             float* __restrict__ pos) {
  __shared__ unsigned short As[2][BM * BK];   // 2 x 16 KB
  __shared__ unsigned short Bs[2][BM * BK];   // 2 x 16 KB

  // XCD-contiguous tile assignment (2080 = 8*260, bijective)
  const int bid = blockIdx.x;
  const int t   = (bid & 7) * (NTRI / 8) + (bid >> 3);
  // decode triangular index t -> (ti, tj), ti<=tj
  int ti = (int)((129.0f - sqrtf(16641.0f - 8.0f * (float)t)) * 0.5f);
  while (ti * (129 - ti) / 2 > t) --ti;
  while ((ti + 1) * (128 - ti) / 2 <= t) ++ti;
  const int tj = ti + (t - ti * (129 - ti) / 2);
  const int rowTile = ti * BM, colTile = tj * BM;
  const bool diag = (ti == tj);
  const bool posT = (tj == ti + B_ / BM);

  const int tid = threadIdx.x, lane = tid & 63, wave = tid >> 6;
  const int wr = wave >> 1, wc = wave & 1;
  const int llo = lane & 15, lhi = lane >> 4;

  // staging offsets: tile = 128 rows x 8 chunks(16B); 4 rounds of 256 chunks.
  // source pre-swizzled (chunk ^= row&7), LDS linear (both-sides rule #21)
  unsigned offA[4], offB[4], ldsOf[4];
#pragma unroll
  for (int r = 0; r < 4; ++r) {
    int ch = r * 256 + tid, row = ch >> 3;
    int sc = ((ch & 7) ^ (row & 7)) << 3;
    offA[r]  = (unsigned)(rowTile + row) * D_ + sc;
    offB[r]  = (unsigned)(colTile + row) * D_ + sc;
    ldsOf[r] = ch * 8;
  }
  // fragment element-offsets (same involution on read)
  unsigned fA[2][4], fB[2][4];
#pragma unroll
  for (int ks = 0; ks < 2; ++ks)
#pragma unroll
    for (int m = 0; m < 4; ++m) {
      int chc = ks * 4 + lhi;
      int ra  = wr * 64 + m * 16 + llo;
      fA[ks][m] = (unsigned)(ra * 8 + (chc ^ (ra & 7))) * 8;
      int rb  = wc * 64 + m * 16 + llo;
      fB[ks][m] = (unsigned)(rb * 8 + (chc ^ (rb & 7))) * 8;
    }

  // prologue: stage tile 0 -> buf 0
#pragma unroll
  for (int r = 0; r < 4; ++r) GLOAD_LDS16(E + offA[r], &As[0][ldsOf[r]]);
#pragma unroll
  for (int r = 0; r < 4; ++r) GLOAD_LDS16(E + offB[r], &Bs[0][ldsOf[r]]);

  f32x4 acc[4][4] = {};

#pragma unroll
  for (int kt = 0; kt < NK; ++kt) {
    const int c = kt & 1;
    const unsigned short* Ac = &As[c][0];
    const unsigned short* Bc = &Bs[c][0];
    unsigned short* An = &As[c ^ 1][0];
    unsigned short* Bn = &Bs[c ^ 1][0];
    const unsigned kn = (unsigned)(kt + 1) * BK;

    // ---- phase 0 (ks = 0) ----
    if (kt + 1 < NK) {
#pragma unroll
      for (int r = 0; r < 4; ++r) GLOAD_LDS16(E + offA[r] + kn, An + ldsOf[r]);
      asm volatile("s_waitcnt vmcnt(4)" ::: "memory");  // tile kt landed; 4 newest in flight
    } else {
      asm volatile("s_waitcnt vmcnt(0)" ::: "memory");
    }
    __builtin_amdgcn_s_barrier();          // all waves' staging of tile kt visible
    __builtin_amdgcn_sched_barrier(0);     // no reads hoist above this point
    {
      bf16x8 ar[4], br[4];
#pragma unroll
      for (int m = 0; m < 4; ++m) ar[m] = *(const bf16x8*)(Ac + fA[0][m]);
#pragma unroll
      for (int n = 0; n < 4; ++n) br[n] = *(const bf16x8*)(Bc + fB[0][n]);
      __builtin_amdgcn_s_setprio(1);
#pragma unroll
      for (int m = 0; m < 4; ++m)
#pragma unroll
        for (int n = 0; n < 4; ++n)
          acc[m][n] = __builtin_amdgcn_mfma_f32_16x16x32_bf16(ar[m], br[n], acc[m][n], 0, 0, 0);
      __builtin_amdgcn_s_setprio(0);
    }
    __builtin_amdgcn_s_barrier();

    // ---- phase 1 (ks = 1) ----
    if (kt + 1 < NK) {
#pragma unroll
      for (int r = 0; r < 4; ++r) GLOAD_LDS16(E + offB[r] + kn, Bn + ldsOf[r]);
    }
    {
      bf16x8 ar[4], br[4];
#pragma unroll
      for (int m = 0; m < 4; ++m) ar[m] = *(const bf16x8*)(Ac + fA[1][m]);
#pragma unroll
      for (int n = 0; n < 4; ++n) br[n] = *(const bf16x8*)(Bc + fB[1][n]);
      __builtin_amdgcn_s_setprio(1);
#pragma unroll
      for (int m = 0; m < 4; ++m)
#pragma unroll
        for (int n = 0; n < 4; ++n)
          acc[m][n] = __builtin_amdgcn_mfma_f32_16x16x32_bf16(ar[m], br[n], acc[m][n], 0, 0, 0);
      __builtin_amdgcn_s_setprio(0);
    }
    __builtin_amdgcn_s_barrier();          // reads of buf c done -> next iter may overwrite
  }

  // --- epilogue ---
  // C/D layout: col = lane&15, row = (lane>>4)*4 + reg   [m89-verified]
  float cs[4] = {0.f, 0.f, 0.f, 0.f};
#pragma unroll
  for (int m = 0; m < 4; ++m) {
    float rs[4] = {0.f, 0.f, 0.f, 0.f};
#pragma unroll
    for (int n = 0; n < 4; ++n) {
      int gc = colTile + wc * 64 + n * 16 + llo;
#pragma unroll
      for (int jj = 0; jj < 4; ++jj) {
        int gr = rowTile + wr * 64 + m * 16 + lhi * 4 + jj;
        float s = acc[m][n][jj] * INV_T;
        if (posT && gc - gr == B_) pos[gr] = s;   // s[r][r+B], unique writer
        float e = __expf(s);
        e = (diag && gr == gc) ? 0.0f : e;
        rs[jj] += e;
        cs[n]  += e;
      }
    }
#pragma unroll
    for (int jj = 0; jj < 4; ++jj) {
      float v = rs[jj];
      v += __shfl_xor(v, 1);
      v += __shfl_xor(v, 2);
      v += __shfl_xor(v, 4);
      v += __shfl_xor(v, 8);
      if (llo == 0) {
        int gr = rowTile + wr * 64 + m * 16 + lhi * 4 + jj;
        atomicAdd(&L[gr], v);
      }
    }
  }
  if (!diag) {
    // column sums = row sums of mirrored tile (j,i)
#pragma unroll
    for (int n = 0; n < 4; ++n) {
      float v = cs[n];
      v += __shfl_xor(v, 16);
      v += __shfl_xor(v, 32);
      if (lhi == 0) {
        int gc = colTile + wc * 64 + n * 16 + llo;
        atomicAdd(&L[gc], v);
      }
    }
  }
}

// ---------------------------------------------------------------------------
// Kernel 3: single block: nll_r = log(L[r]) - pos[r mod B]; mean -> out.
// ---------------------------------------------------------------------------
__global__ void ntx_fin(const float* __restrict__ L, const float* __restrict__ pos,
                        float* __restrict__ out) {
  int tid = threadIdx.x;
  float s = 0.f;
#pragma unroll
  for (int k = 0; k < TB_ / 256; ++k) {
    int r = k * 256 + tid;
    s += __logf(L[r]) - pos[r & (B_ - 1)];
  }
#pragma unroll
  for (int off = 1; off < 64; off <<= 1) s += __shfl_xor(s, off);
  __shared__ float sm[4];
  if ((tid & 63) == 0) sm[tid >> 6] = s;
  __syncthreads();
  if (tid == 0) out[0] = (sm[0] + sm[1] + sm[2] + sm[3]) * (1.0f / TB_);
}

// ---------------------------------------------------------------------------
extern "C" void kernel_launch(void* const* d_in, const int* in_sizes, int n_in,
                              void* d_out, int out_size, void* d_ws, size_t ws_size,
                              hipStream_t stream) {
  const float* e1 = (const float*)d_in[0];
  const float* e2 = (const float*)d_in[1];
  float* out = (float*)d_out;
  unsigned short* E = (unsigned short*)d_ws;                        // 8 MB bf16
  float* L   = (float*)((char*)d_ws + (size_t)TB_ * D_ * 2);        // 32 KB
  float* pos = L + TB_;                                             // 16 KB

  ntx_prep<<<2048, 256, 0, stream>>>(e1, e2, E, L);
  ntx_sim<<<NTRI, 256, 0, stream>>>(E, L, pos);
  ntx_fin<<<1, 256, 0, stream>>>(L, pos, out);
}

// Round 4
// 109.214 us; speedup vs baseline: 1.0413x; 1.0413x over previous
//
#include <hip/hip_runtime.h>
#include <hip/hip_bf16.h>

#define B_    4096
#define D_    512
#define TB_   8192        // 2B rows
#define BM    256
#define BK    64
#define NK8   8           // K-tiles (D_/BK)
#define NT    32          // TB_/BM
#define NTRI  528         // NT*(NT+1)/2
#define INV_T 14.285714285714286f   // 1/0.07

typedef __attribute__((ext_vector_type(8))) short bf16x8;
typedef __attribute__((ext_vector_type(4))) float f32x4;
typedef __attribute__((ext_vector_type(8))) unsigned short ushort8;

#define GLOAD_LDS16(gp, lp)                                                        \
  __builtin_amdgcn_global_load_lds((const __attribute__((address_space(1))) void*)(gp), \
                                   (__attribute__((address_space(3))) void*)(lp),  \
                                   16, 0, 0)

__device__ __forceinline__ unsigned short f2bf(float f) {
  unsigned int x = __float_as_uint(f);
  x += 0x7fffu + ((x >> 16) & 1u);   // round-to-nearest-even
  return (unsigned short)(x >> 16);
}

// ---------------------------------------------------------------------------
// Kernel 1: concat+cast fp32 -> bf16 (E[8192][512]), zero L[8192].
// ---------------------------------------------------------------------------
__global__ void ntx_prep(const float* __restrict__ a, const float* __restrict__ b,
                         unsigned short* __restrict__ E, float* __restrict__ L) {
  int t = blockIdx.x * blockDim.x + threadIdx.x;      // 0..524287
  int i = t * 8;
  const float* src = (i < B_ * D_) ? (a + i) : (b + (i - B_ * D_));
  float4 v0 = ((const float4*)src)[0];
  float4 v1 = ((const float4*)src)[1];
  ushort8 o;
  o[0] = f2bf(v0.x); o[1] = f2bf(v0.y); o[2] = f2bf(v0.z); o[3] = f2bf(v0.w);
  o[4] = f2bf(v1.x); o[5] = f2bf(v1.y); o[6] = f2bf(v1.z); o[7] = f2bf(v1.w);
  *(ushort8*)(E + i) = o;
  if (t < TB_) L[t] = 0.0f;
}

// ---------------------------------------------------------------------------
// Kernel 2: 256x256-tile 8-phase pipelined sim + exp row/col sums.
// 512 threads = 8 waves (2M x 4N), wave tile 128x64. LDS 128 KB:
// As[2 dbuf][2 half(128 rows)][128x64 bf16], same for Bs. Per K-tile k
// (buf k&1), 4 phases = 4 C-quadrants x 16 MFMA. Staging stagger:
//   p1: T(k+1).B1   p2: T(k+2).A0   p3: T(k+2).B0   p4: T(k+2).A1
// vmcnt(6) at p4 (3 halves = 6 loads stay in flight). Chunk-XOR swizzle
// (chunk ^= row&7) on BOTH global source and ds_read (0-conflict verified).
// Triangular tiles; off-diag adds col-sums (mirror); pos tiles tj==ti+16.
// ---------------------------------------------------------------------------
#define RD_A(aBase, MH)                                                          \
  do { _Pragma("unroll") for (int ks = 0; ks < 2; ++ks)                          \
       _Pragma("unroll") for (int m = 0; m < 4; ++m)                             \
         aF[ks][m] = *(const bf16x8*)((aBase) + fk[ks] + (MH) * 4096 + m * 1024);\
  } while (0)
#define RD_B(dst, bBase, NH)                                                     \
  do { _Pragma("unroll") for (int ks = 0; ks < 2; ++ks)                          \
       _Pragma("unroll") for (int n = 0; n < 2; ++n)                             \
         dst[ks][n] = *(const bf16x8*)((bBase) + fk[ks] + (NH) * 2048 + n * 1024);\
  } while (0)
#define MM(MH, NH, BF)                                                           \
  do { __builtin_amdgcn_s_setprio(1);                                            \
       _Pragma("unroll") for (int m = 0; m < 4; ++m)                             \
       _Pragma("unroll") for (int n = 0; n < 2; ++n)                             \
       _Pragma("unroll") for (int ks = 0; ks < 2; ++ks)                          \
         acc[(MH)*4+m][(NH)*2+n] = __builtin_amdgcn_mfma_f32_16x16x32_bf16(      \
             aF[ks][m], BF[ks][n], acc[(MH)*4+m][(NH)*2+n], 0, 0, 0);            \
       __builtin_amdgcn_s_setprio(0);                                            \
  } while (0)
#define PH_SYNC()                                                                \
  do { __builtin_amdgcn_s_barrier();                                             \
       asm volatile("s_waitcnt lgkmcnt(0)" ::: "memory");                        \
       __builtin_amdgcn_sched_barrier(0);                                        \
  } while (0)
#define PH_END() __builtin_amdgcn_s_barrier()
#define STG_A(nb, h, kt)                                                         \
  do { GLOAD_LDS16(E + offA[0][h] + (kt) * BK, &As[nb][h][ldsCh[0]]);            \
       GLOAD_LDS16(E + offA[1][h] + (kt) * BK, &As[nb][h][ldsCh[1]]);            \
  } while (0)
#define STG_B(nb, h, kt)                                                         \
  do { GLOAD_LDS16(E + offB[0][h] + (kt) * BK, &Bs[nb][h][ldsCh[0]]);            \
       GLOAD_LDS16(E + offB[1][h] + (kt) * BK, &Bs[nb][h][ldsCh[1]]);            \
  } while (0)

__global__ __launch_bounds__(512, 2)
void ntx_sim(const unsigned short* __restrict__ E, float* __restrict__ L,
             float* __restrict__ pos) {
  __shared__ unsigned short As[2][2][8192];   // 64 KB
  __shared__ unsigned short Bs[2][2][8192];   // 64 KB

  // XCD-contiguous bijective swizzle (528 = 8*66)
  const int bid = blockIdx.x;
  const int t = (bid & 7) * (NTRI / 8) + (bid >> 3);
  // triangular decode: tiles before row ti = ti*(65-ti)/2
  int ti = (int)((65.0f - sqrtf(4225.0f - 8.0f * (float)t)) * 0.5f);
  while (ti * (65 - ti) / 2 > t) --ti;
  while ((ti + 1) * (64 - ti) / 2 <= t) ++ti;
  const int tj = ti + (t - ti * (65 - ti) / 2);
  const int rowTile = ti * BM, colTile = tj * BM;
  const bool diag = (ti == tj);
  const bool posT = (tj == ti + B_ / BM);

  const int tid = threadIdx.x, lane = tid & 63, wave = tid >> 6;
  const int wr = wave >> 2;          // 0..1: 128-row band
  const int wn = wave & 3;           // 0..3: 64-col band
  const int llo = lane & 15, lhi = lane >> 4;

  // fragment read bases (per dbuf) + swizzled intra-half offsets
  const unsigned short* aBb[2] = { &As[0][wr][0], &As[1][wr][0] };
  const unsigned short* bBb[2] = { &Bs[0][wn >> 1][0] + (wn & 1) * 4096,
                                   &Bs[1][wn >> 1][0] + (wn & 1) * 4096 };
  unsigned fk[2];
#pragma unroll
  for (int ks = 0; ks < 2; ++ks)
    fk[ks] = (unsigned)(llo * 64 + ((ks * 4 + lhi) ^ (llo & 7)) * 8);

  // staging: half = 128 rows x 8 chunks(16B) = 1024 chunks; 2 rounds x 512 thr
  unsigned offA[2][2], offB[2][2], ldsCh[2];   // [round][half]
#pragma unroll
  for (int r = 0; r < 2; ++r) {
    int ch = r * 512 + tid, row = ch >> 3, cc = ch & 7;
    int sc = (cc ^ (row & 7)) << 3;            // pre-swizzled source col
    ldsCh[r] = (unsigned)ch * 8;
#pragma unroll
    for (int h = 0; h < 2; ++h) {
      offA[r][h] = (unsigned)(rowTile + h * 128 + row) * D_ + sc;
      offB[r][h] = (unsigned)(colTile + h * 128 + row) * D_ + sc;
    }
  }

  // prologue: stage T0 fully + T1.{A0,B0,A1}; keep T1's 3 halves in flight
  STG_A(0, 0, 0); STG_B(0, 0, 0); STG_A(0, 1, 0); STG_B(0, 1, 0);
  STG_A(1, 0, 1); STG_B(1, 0, 1); STG_A(1, 1, 1);
  asm volatile("s_waitcnt vmcnt(6)" ::: "memory");
  __builtin_amdgcn_s_barrier();

  f32x4 acc[8][4] = {};
  bf16x8 aF[2][4], bF0[2][2], bF1[2][2];

#pragma unroll
  for (int k = 0; k < NK8; ++k) {
    const unsigned short* aB = aBb[k & 1];
    const unsigned short* bB = bBb[k & 1];
    const int nbn = (k + 1) & 1;   // buffer of tile k+1
    const int nb2 = k & 1;         // buffer of tile k+2
    // ---- p1: quadrant (mh0, nh0) ----
    RD_A(aB, 0); RD_B(bF0, bB, 0);
    if (k + 1 < NK8) STG_B(nbn, 1, k + 1);
    PH_SYNC(); MM(0, 0, bF0); PH_END();
    // ---- p2: (mh0, nh1) ----
    RD_B(bF1, bB, 1);
    if (k + 2 < NK8) STG_A(nb2, 0, k + 2);
    PH_SYNC(); MM(0, 1, bF1); PH_END();
    // ---- p3: (mh1, nh0) ----
    RD_A(aB, 1);
    if (k + 2 < NK8) STG_B(nb2, 0, k + 2);
    PH_SYNC(); MM(1, 0, bF0); PH_END();
    // ---- p4: (mh1, nh1) + counted wait ----
    if (k + 2 < NK8) STG_A(nb2, 1, k + 2);
    if (k < NK8 - 2) { asm volatile("s_waitcnt vmcnt(6)" ::: "memory"); }
    else if (k == NK8 - 2) { asm volatile("s_waitcnt vmcnt(0)" ::: "memory"); }
    PH_SYNC(); MM(1, 1, bF1); PH_END();
  }

  // --- epilogue ---
  // gr = rowTile + wr*128 + am*16 + lhi*4 + jj ; gc = colTile + wn*64 + an*16 + llo
  float cs[4] = {0.f, 0.f, 0.f, 0.f};
#pragma unroll
  for (int am = 0; am < 8; ++am) {
    float rs[4] = {0.f, 0.f, 0.f, 0.f};
#pragma unroll
    for (int an = 0; an < 4; ++an) {
      int gc = colTile + wn * 64 + an * 16 + llo;
#pragma unroll
      for (int jj = 0; jj < 4; ++jj) {
        int gr = rowTile + wr * 128 + am * 16 + lhi * 4 + jj;
        float s = acc[am][an][jj] * INV_T;
        if (posT && gc - gr == B_) pos[gr] = s;   // s[r][r+B], unique writer
        float e = __expf(s);
        e = (diag && gr == gc) ? 0.0f : e;
        rs[jj] += e;
        cs[an] += e;
      }
    }
#pragma unroll
    for (int jj = 0; jj < 4; ++jj) {
      float v = rs[jj];
      v += __shfl_xor(v, 1);
      v += __shfl_xor(v, 2);
      v += __shfl_xor(v, 4);
      v += __shfl_xor(v, 8);
      if (llo == 0) {
        int gr = rowTile + wr * 128 + am * 16 + lhi * 4 + jj;
        atomicAdd(&L[gr], v);
      }
    }
  }
  if (!diag) {
    // column sums = row sums of mirrored tile (j,i)
#pragma unroll
    for (int an = 0; an < 4; ++an) {
      float v = cs[an];
      v += __shfl_xor(v, 16);
      v += __shfl_xor(v, 32);
      if (lhi == 0) {
        int gc = colTile + wn * 64 + an * 16 + llo;
        atomicAdd(&L[gc], v);
      }
    }
  }
}

// ---------------------------------------------------------------------------
// Kernel 3: single block: nll_r = log(L[r]) - pos[r mod B]; mean -> out.
// ---------------------------------------------------------------------------
__global__ void ntx_fin(const float* __restrict__ L, const float* __restrict__ pos,
                        float* __restrict__ out) {
  int tid = threadIdx.x;
  float s = 0.f;
#pragma unroll
  for (int k = 0; k < TB_ / 256; ++k) {
    int r = k * 256 + tid;
    s += __logf(L[r]) - pos[r & (B_ - 1)];
  }
#pragma unroll
  for (int off = 1; off < 64; off <<= 1) s += __shfl_xor(s, off);
  __shared__ float sm[4];
  if ((tid & 63) == 0) sm[tid >> 6] = s;
  __syncthreads();
  if (tid == 0) out[0] = (sm[0] + sm[1] + sm[2] + sm[3]) * (1.0f / TB_);
}

// ---------------------------------------------------------------------------
extern "C" void kernel_launch(void* const* d_in, const int* in_sizes, int n_in,
                              void* d_out, int out_size, void* d_ws, size_t ws_size,
                              hipStream_t stream) {
  const float* e1 = (const float*)d_in[0];
  const float* e2 = (const float*)d_in[1];
  float* out = (float*)d_out;
  unsigned short* E = (unsigned short*)d_ws;                        // 8 MB bf16
  float* L   = (float*)((char*)d_ws + (size_t)TB_ * D_ * 2);        // 32 KB
  float* pos = L + TB_;                                             // 16 KB

  ntx_prep<<<2048, 256, 0, stream>>>(e1, e2, E, L);
  ntx_sim<<<NTRI, 512, 0, stream>>>(E, L, pos);
  ntx_fin<<<1, 256, 0, stream>>>(L, pos, out);
}

// Round 5
// 107.215 us; speedup vs baseline: 1.0608x; 1.0186x over previous
//
#include <hip/hip_runtime.h>
#include <hip/hip_bf16.h>

#define B_    4096
#define D_    512
#define TB_   8192        // 2B rows
#define BM    256
#define BK    64
#define NK8   8           // K-tiles (D_/BK)
#define NT    32          // TB_/BM
#define NTRI  528         // NT*(NT+1)/2
#define INV_T 14.285714285714286f   // 1/0.07

typedef __attribute__((ext_vector_type(8))) short bf16x8;
typedef __attribute__((ext_vector_type(4))) float f32x4;
typedef __attribute__((ext_vector_type(8))) unsigned short ushort8;

#define GLOAD_LDS16(gp, lp)                                                        \
  __builtin_amdgcn_global_load_lds((const __attribute__((address_space(1))) void*)(gp), \
                                   (__attribute__((address_space(3))) void*)(lp),  \
                                   16, 0, 0)

__device__ __forceinline__ unsigned short f2bf(float f) {
  unsigned int x = __float_as_uint(f);
  x += 0x7fffu + ((x >> 16) & 1u);   // round-to-nearest-even
  return (unsigned short)(x >> 16);
}

// ---------------------------------------------------------------------------
// Kernel 1: concat+cast fp32 -> bf16 (E[8192][512]), zero L[8192].
// ---------------------------------------------------------------------------
__global__ void ntx_prep(const float* __restrict__ a, const float* __restrict__ b,
                         unsigned short* __restrict__ E, float* __restrict__ L) {
  int t = blockIdx.x * blockDim.x + threadIdx.x;      // 0..524287
  int i = t * 8;
  const float* src = (i < B_ * D_) ? (a + i) : (b + (i - B_ * D_));
  float4 v0 = ((const float4*)src)[0];
  float4 v1 = ((const float4*)src)[1];
  ushort8 o;
  o[0] = f2bf(v0.x); o[1] = f2bf(v0.y); o[2] = f2bf(v0.z); o[3] = f2bf(v0.w);
  o[4] = f2bf(v1.x); o[5] = f2bf(v1.y); o[6] = f2bf(v1.z); o[7] = f2bf(v1.w);
  *(ushort8*)(E + i) = o;
  if (t < TB_) L[t] = 0.0f;
}

// ---------------------------------------------------------------------------
// Kernel 2: 256x256-tile 8-phase pipelined sim + exp row/col sums.
// 512 threads = 8 waves (2M x 4N), wave tile 128x64. LDS 128 KB.
// Race-free stagger (A halves are ds_read at p1 AND p3; B halves at p1 AND
// p2 -> A regions free only after p3's drain, B after p2's):
//   p3: stage T(k+2).{B0,B1}   p4: stage T(k+2).{A0,A1}, then vmcnt(8)
//   (T(k+1)'s 8 loads landed; T(k+2)'s 8 stay in flight across barriers).
// NO sched_barrier in the loop (m141: order-pinning = 3x slowdown).
// Chunk-XOR swizzle (chunk ^= row&7) on BOTH global source and ds_read.
// Triangular tiles; off-diag adds col-sums (mirror); pos tiles tj==ti+16.
// ---------------------------------------------------------------------------
#define RD_A(aBase, MH)                                                          \
  do { _Pragma("unroll") for (int ks = 0; ks < 2; ++ks)                          \
       _Pragma("unroll") for (int m = 0; m < 4; ++m)                             \
         aF[ks][m] = *(const bf16x8*)((aBase) + fk[ks] + (MH) * 4096 + m * 1024);\
  } while (0)
#define RD_B(dst, bBase, NH)                                                     \
  do { _Pragma("unroll") for (int ks = 0; ks < 2; ++ks)                          \
       _Pragma("unroll") for (int n = 0; n < 2; ++n)                             \
         dst[ks][n] = *(const bf16x8*)((bBase) + fk[ks] + (NH) * 2048 + n * 1024);\
  } while (0)
#define MM(MH, NH, BF)                                                           \
  do { __builtin_amdgcn_s_setprio(1);                                            \
       _Pragma("unroll") for (int m = 0; m < 4; ++m)                             \
       _Pragma("unroll") for (int n = 0; n < 2; ++n)                             \
       _Pragma("unroll") for (int ks = 0; ks < 2; ++ks)                          \
         acc[(MH)*4+m][(NH)*2+n] = __builtin_amdgcn_mfma_f32_16x16x32_bf16(      \
             aF[ks][m], BF[ks][n], acc[(MH)*4+m][(NH)*2+n], 0, 0, 0);            \
       __builtin_amdgcn_s_setprio(0);                                            \
  } while (0)
#define PH_SYNC()                                                                \
  do { __builtin_amdgcn_s_barrier();                                             \
       asm volatile("s_waitcnt lgkmcnt(0)" ::: "memory");                        \
  } while (0)
#define PH_END() __builtin_amdgcn_s_barrier()
#define STG_A(nb, h, kt)                                                         \
  do { GLOAD_LDS16(E + offA[0][h] + (kt) * BK, &As[nb][h][ldsCh[0]]);            \
       GLOAD_LDS16(E + offA[1][h] + (kt) * BK, &As[nb][h][ldsCh[1]]);            \
  } while (0)
#define STG_B(nb, h, kt)                                                         \
  do { GLOAD_LDS16(E + offB[0][h] + (kt) * BK, &Bs[nb][h][ldsCh[0]]);            \
       GLOAD_LDS16(E + offB[1][h] + (kt) * BK, &Bs[nb][h][ldsCh[1]]);            \
  } while (0)

__global__ __launch_bounds__(512, 2)
void ntx_sim(const unsigned short* __restrict__ E, float* __restrict__ L,
             float* __restrict__ pos) {
  __shared__ unsigned short As[2][2][8192];   // 64 KB
  __shared__ unsigned short Bs[2][2][8192];   // 64 KB

  // XCD-contiguous bijective swizzle (528 = 8*66)
  const int bid = blockIdx.x;
  const int t = (bid & 7) * (NTRI / 8) + (bid >> 3);
  // triangular decode: tiles before row ti = ti*(65-ti)/2
  int ti = (int)((65.0f - sqrtf(4225.0f - 8.0f * (float)t)) * 0.5f);
  while (ti * (65 - ti) / 2 > t) --ti;
  while ((ti + 1) * (64 - ti) / 2 <= t) ++ti;
  const int tj = ti + (t - ti * (65 - ti) / 2);
  const int rowTile = ti * BM, colTile = tj * BM;
  const bool diag = (ti == tj);
  const bool posT = (tj == ti + B_ / BM);

  const int tid = threadIdx.x, lane = tid & 63, wave = tid >> 6;
  const int wr = wave >> 2;          // 0..1: 128-row band
  const int wn = wave & 3;           // 0..3: 64-col band
  const int llo = lane & 15, lhi = lane >> 4;

  // fragment read bases (per dbuf) + swizzled intra-half offsets
  const unsigned short* aBb[2] = { &As[0][wr][0], &As[1][wr][0] };
  const unsigned short* bBb[2] = { &Bs[0][wn >> 1][0] + (wn & 1) * 4096,
                                   &Bs[1][wn >> 1][0] + (wn & 1) * 4096 };
  unsigned fk[2];
#pragma unroll
  for (int ks = 0; ks < 2; ++ks)
    fk[ks] = (unsigned)(llo * 64 + ((ks * 4 + lhi) ^ (llo & 7)) * 8);

  // staging: half = 128 rows x 8 chunks(16B) = 1024 chunks; 2 rounds x 512 thr
  unsigned offA[2][2], offB[2][2], ldsCh[2];   // [round][half]
#pragma unroll
  for (int r = 0; r < 2; ++r) {
    int ch = r * 512 + tid, row = ch >> 3, cc = ch & 7;
    int sc = (cc ^ (row & 7)) << 3;            // pre-swizzled source col
    ldsCh[r] = (unsigned)ch * 8;
#pragma unroll
    for (int h = 0; h < 2; ++h) {
      offA[r][h] = (unsigned)(rowTile + h * 128 + row) * D_ + sc;
      offB[r][h] = (unsigned)(colTile + h * 128 + row) * D_ + sc;
    }
  }

  // prologue: stage T0 fully, then T1 fully; T1's 8 loads stay in flight
  STG_A(0, 0, 0); STG_B(0, 0, 0); STG_A(0, 1, 0); STG_B(0, 1, 0);
  STG_A(1, 0, 1); STG_B(1, 0, 1); STG_A(1, 1, 1); STG_B(1, 1, 1);
  asm volatile("s_waitcnt vmcnt(8)" ::: "memory");
  __builtin_amdgcn_s_barrier();

  f32x4 acc[8][4] = {};
  bf16x8 aF[2][4], bF0[2][2], bF1[2][2];

#pragma unroll
  for (int k = 0; k < NK8; ++k) {
    const unsigned short* aB = aBb[k & 1];
    const unsigned short* bB = bBb[k & 1];
    const int nb2 = k & 1;         // buffer of tile k+2 (= current buffer)
    // ---- p1: quadrant (mh0, nh0) ----
    RD_A(aB, 0); RD_B(bF0, bB, 0);
    PH_SYNC(); MM(0, 0, bF0); PH_END();
    // ---- p2: (mh0, nh1) ----
    RD_B(bF1, bB, 1);
    PH_SYNC(); MM(0, 1, bF1); PH_END();
    // ---- p3: (mh1, nh0); B regions free after p2's drain ----
    RD_A(aB, 1);
    if (k + 2 < NK8) { STG_B(nb2, 0, k + 2); STG_B(nb2, 1, k + 2); }
    PH_SYNC(); MM(1, 0, bF0); PH_END();
    // ---- p4: (mh1, nh1); A regions free after p3's drain ----
    if (k + 2 < NK8) { STG_A(nb2, 0, k + 2); STG_A(nb2, 1, k + 2); }
    if (k <= NK8 - 3)      { asm volatile("s_waitcnt vmcnt(8)" ::: "memory"); }
    else if (k == NK8 - 2) { asm volatile("s_waitcnt vmcnt(0)" ::: "memory"); }
    PH_SYNC(); MM(1, 1, bF1); PH_END();
  }

  // --- epilogue ---
  // gr = rowTile + wr*128 + am*16 + lhi*4 + jj ; gc = colTile + wn*64 + an*16 + llo
  float cs[4] = {0.f, 0.f, 0.f, 0.f};
#pragma unroll
  for (int am = 0; am < 8; ++am) {
    float rs[4] = {0.f, 0.f, 0.f, 0.f};
#pragma unroll
    for (int an = 0; an < 4; ++an) {
      int gc = colTile + wn * 64 + an * 16 + llo;
#pragma unroll
      for (int jj = 0; jj < 4; ++jj) {
        int gr = rowTile + wr * 128 + am * 16 + lhi * 4 + jj;
        float s = acc[am][an][jj] * INV_T;
        if (posT && gc - gr == B_) pos[gr] = s;   // s[r][r+B], unique writer
        float e = __expf(s);
        e = (diag && gr == gc) ? 0.0f : e;
        rs[jj] += e;
        cs[an] += e;
      }
    }
#pragma unroll
    for (int jj = 0; jj < 4; ++jj) {
      float v = rs[jj];
      v += __shfl_xor(v, 1);
      v += __shfl_xor(v, 2);
      v += __shfl_xor(v, 4);
      v += __shfl_xor(v, 8);
      if (llo == 0) {
        int gr = rowTile + wr * 128 + am * 16 + lhi * 4 + jj;
        atomicAdd(&L[gr], v);
      }
    }
  }
  if (!diag) {
    // column sums = row sums of mirrored tile (j,i)
#pragma unroll
    for (int an = 0; an < 4; ++an) {
      float v = cs[an];
      v += __shfl_xor(v, 16);
      v += __shfl_xor(v, 32);
      if (lhi == 0) {
        int gc = colTile + wn * 64 + an * 16 + llo;
        atomicAdd(&L[gc], v);
      }
    }
  }
}

// ---------------------------------------------------------------------------
// Kernel 3: single block: nll_r = log(L[r]) - pos[r mod B]; mean -> out.
// ---------------------------------------------------------------------------
__global__ void ntx_fin(const float* __restrict__ L, const float* __restrict__ pos,
                        float* __restrict__ out) {
  int tid = threadIdx.x;
  float s = 0.f;
#pragma unroll
  for (int k = 0; k < TB_ / 256; ++k) {
    int r = k * 256 + tid;
    s += __logf(L[r]) - pos[r & (B_ - 1)];
  }
#pragma unroll
  for (int off = 1; off < 64; off <<= 1) s += __shfl_xor(s, off);
  __shared__ float sm[4];
  if ((tid & 63) == 0) sm[tid >> 6] = s;
  __syncthreads();
  if (tid == 0) out[0] = (sm[0] + sm[1] + sm[2] + sm[3]) * (1.0f / TB_);
}

// ---------------------------------------------------------------------------
extern "C" void kernel_launch(void* const* d_in, const int* in_sizes, int n_in,
                              void* d_out, int out_size, void* d_ws, size_t ws_size,
                              hipStream_t stream) {
  const float* e1 = (const float*)d_in[0];
  const float* e2 = (const float*)d_in[1];
  float* out = (float*)d_out;
  unsigned short* E = (unsigned short*)d_ws;                        // 8 MB bf16
  float* L   = (float*)((char*)d_ws + (size_t)TB_ * D_ * 2);        // 32 KB
  float* pos = L + TB_;                                             // 16 KB

  ntx_prep<<<2048, 256, 0, stream>>>(e1, e2, E, L);
  ntx_sim<<<NTRI, 512, 0, stream>>>(E, L, pos);
  ntx_fin<<<1, 256, 0, stream>>>(L, pos, out);
}